// Round 1
// baseline (599.420 us; speedup 1.0000x reference)
//
#include <hip/hip_runtime.h>

// Problem constants (B,N,HD,NH,KVH fixed by reference)
#define BB   2
#define NN   2048
#define HDIM 2048
#define NHD  16
#define KVHD 4
#define DD   128
#define KVW  1024          // kv buffer width: k[0:512] | v[512:1024]
#define MTOK (BB*NN)       // 4096 token rows

typedef _Float16 h8 __attribute__((ext_vector_type(8)));
typedef _Float16 h4 __attribute__((ext_vector_type(4)));
typedef float    f4 __attribute__((ext_vector_type(4)));

static __device__ __forceinline__ f4 mfma16(h8 a, h8 b, f4 c) {
    return __builtin_amdgcn_mfma_f32_16x16x32_f16(a, b, c, 0, 0, 0);
}

// async global->LDS, 16B per lane. LDS dst must be wave-uniform base + lane*16.
static __device__ __forceinline__ void gload_lds16(const void* g, void* l) {
    __builtin_amdgcn_global_load_lds(
        (const __attribute__((address_space(1))) void*)g,
        (__attribute__((address_space(3))) void*)l, 16, 0, 0);
}

// ---------------- RMSNorm (fp32 in, f16 out) ----------------
__global__ __launch_bounds__(256) void rmsnorm_k(const float* __restrict__ t,
                                                 const float* __restrict__ wn,
                                                 _Float16* __restrict__ xh) {
    const int row = blockIdx.x, tid = threadIdx.x;
    const float* rp = t + (size_t)row * HDIM;
    float4 v[2];
    float ss = 0.f;
    #pragma unroll
    for (int p = 0; p < 2; ++p) {
        float4 x = *(const float4*)(rp + (p * 256 + tid) * 4);
        v[p] = x;
        ss += x.x * x.x + x.y * x.y + x.z * x.z + x.w * x.w;
    }
    #pragma unroll
    for (int off = 32; off; off >>= 1) ss += __shfl_xor(ss, off, 64);
    __shared__ float sred[4];
    if ((tid & 63) == 0) sred[tid >> 6] = ss;
    __syncthreads();
    float rs = rsqrtf((sred[0] + sred[1] + sred[2] + sred[3]) * (1.0f / HDIM)
                      + 1.1920928955078125e-07f);
    _Float16* op = xh + (size_t)row * HDIM;
    #pragma unroll
    for (int p = 0; p < 2; ++p) {
        int base = (p * 256 + tid) * 4;
        float4 w = *(const float4*)(wn + base);
        h4 o;
        o[0] = (_Float16)(v[p].x * rs * w.x);
        o[1] = (_Float16)(v[p].y * rs * w.y);
        o[2] = (_Float16)(v[p].z * rs * w.z);
        o[3] = (_Float16)(v[p].w * rs * w.w);
        *(h4*)(op + base) = o;
    }
}

// ---------------- fp32 -> f16 convert ----------------
__global__ __launch_bounds__(256) void cvt_k(const float* __restrict__ src,
                                             _Float16* __restrict__ dst, int n) {
    int i = (blockIdx.x * 256 + threadIdx.x) * 4;
    if (i < n) {
        float4 v = *(const float4*)(src + i);
        h4 o; o[0] = (_Float16)v.x; o[1] = (_Float16)v.y;
        o[2] = (_Float16)v.z; o[3] = (_Float16)v.w;
        *(h4*)(dst + i) = o;
    }
}

__global__ void biascat_k(const float* __restrict__ bk, const float* __restrict__ bv,
                          float* __restrict__ bkv) {
    int i = blockIdx.x * 256 + threadIdx.x;   // 1024 total
    bkv[i] = (i < 512) ? bk[i] : bv[i - 512];
}

// ---------------- GEMM  C[M,Nout] = A[M,K] * Bw[Nout,K]^T + bias ----------------
// m97 structure: 128x128 tile, 256 thr (4 waves, 2x2), BK=64, global_load_lds x16.
template <int OUTF32>
__global__ __launch_bounds__(256, 2) void gemm_bt(const _Float16* __restrict__ A,
                                                  const _Float16* __restrict__ Bw,
                                                  const float* __restrict__ bias,
                                                  void* __restrict__ Cout,
                                                  int Ndim, int K) {
    __shared__ _Float16 sA[128 * 64];
    __shared__ _Float16 sB[128 * 64];
    const int tid = threadIdx.x;
    const int lane = tid & 63, w = tid >> 6;
    const int ln = lane & 15, quad = lane >> 4;
    const int wm = w >> 1, wn = w & 1;
    const int m0 = blockIdx.y * 128, n0 = blockIdx.x * 128;

    f4 acc[4][4] = {};
    for (int k0 = 0; k0 < K; k0 += 64) {
        #pragma unroll
        for (int it = 0; it < 4; ++it) {
            int chunk = it * 256 + tid;            // 1024 chunks of 8 halves
            int row = chunk >> 3, kc = (chunk & 7) << 3;
            gload_lds16(A + (size_t)(m0 + row) * K + k0 + kc, sA + chunk * 8);
            gload_lds16(Bw + (size_t)(n0 + row) * K + k0 + kc, sB + chunk * 8);
        }
        __syncthreads();
        #pragma unroll
        for (int kk = 0; kk < 2; ++kk) {
            h8 af[4], bf[4];
            #pragma unroll
            for (int mt = 0; mt < 4; ++mt)
                af[mt] = *(const h8*)&sA[(wm * 64 + mt * 16 + ln) * 64 + kk * 32 + quad * 8];
            #pragma unroll
            for (int nt = 0; nt < 4; ++nt)
                bf[nt] = *(const h8*)&sB[(wn * 64 + nt * 16 + ln) * 64 + kk * 32 + quad * 8];
            #pragma unroll
            for (int mt = 0; mt < 4; ++mt)
                #pragma unroll
                for (int nt = 0; nt < 4; ++nt)
                    acc[mt][nt] = mfma16(af[mt], bf[nt], acc[mt][nt]);
        }
        __syncthreads();
    }
    #pragma unroll
    for (int mt = 0; mt < 4; ++mt) {
        int rowb = m0 + wm * 64 + mt * 16 + quad * 4;   // C: row = quad*4+reg
        #pragma unroll
        for (int nt = 0; nt < 4; ++nt) {
            int col = n0 + wn * 64 + nt * 16 + ln;      // C: col = lane&15
            float bv = bias[col];
            #pragma unroll
            for (int r = 0; r < 4; ++r) {
                float v = acc[mt][nt][r] + bv;
                if (OUTF32)
                    ((float*)Cout)[(size_t)(rowb + r) * Ndim + col] = v;
                else
                    ((_Float16*)Cout)[(size_t)(rowb + r) * Ndim + col] = (_Float16)v;
            }
        }
    }
}

// ---------------- Flash attention, inverted-causal (attend j > i) ----------------
// grid (N/64, NH, B); 256 thr = 4 waves, wave w -> q rows [i0+16w, i0+16w+16)
__global__ __launch_bounds__(256, 2) void attn_k(const _Float16* __restrict__ qh,
                                                 const _Float16* __restrict__ kvp,
                                                 _Float16* __restrict__ ah) {
    __shared__ _Float16 s_k[64 * 128];    // K tile [j][d]
    __shared__ _Float16 s_vt[128 * 64];   // V tile transposed [d][j]
    __shared__ _Float16 s_p[4][16 * 64];  // per-wave P (A-layout round trip)
    const int tid = threadIdx.x;
    const int lane = tid & 63, w = tid >> 6;
    const int ln = lane & 15, quad = lane >> 4;
    const int it0 = blockIdx.x, i0 = it0 * 64;
    const int h = blockIdx.y, b = blockIdx.z;
    const int kvh = h & 3;                 // head h uses kv head h % KVH

    // Q fragments (A-layout): m=lane&15, k=quad*8+j within each 32-chunk
    h8 qf[4];
    const _Float16* qrow = qh + ((size_t)(b * NN + i0 + w * 16 + ln)) * HDIM + h * DD;
    #pragma unroll
    for (int kc = 0; kc < 4; ++kc) qf[kc] = *(const h8*)(qrow + kc * 32 + quad * 8);

    f4 O[8] = {};
    float mrow[4] = {-INFINITY, -INFINITY, -INFINITY, -INFINITY};
    float lrow[4] = {0.f, 0.f, 0.f, 0.f};

    for (int jt = it0; jt < NN / 64; ++jt) {   // tiles with any j > i
        const int j0 = jt * 64;
        // stage K tile (async 16B)
        #pragma unroll
        for (int itr = 0; itr < 4; ++itr) {
            int chunk = itr * 256 + tid;          // 1024 chunks
            int jj = chunk >> 4, kc = (chunk & 15) << 3;
            gload_lds16(kvp + ((size_t)(b * NN + j0 + jj)) * KVW + kvh * DD + kc,
                        s_k + chunk * 8);
        }
        // stage V transposed (scatter b16 writes; 2-way bank alias = free)
        {
            int jj = tid & 63, d0 = (tid >> 6) * 32;
            const _Float16* vsrc =
                kvp + ((size_t)(b * NN + j0 + jj)) * KVW + 512 + kvh * DD + d0;
            #pragma unroll
            for (int u = 0; u < 4; ++u) {
                h8 vv = *(const h8*)(vsrc + u * 8);
                #pragma unroll
                for (int e = 0; e < 8; ++e) s_vt[(d0 + u * 8 + e) * 64 + jj] = vv[e];
            }
        }
        __syncthreads();

        // S = Q K^T  (16 rows x 64 cols per wave)
        f4 sc[4] = {};
        #pragma unroll
        for (int nt = 0; nt < 4; ++nt)
            #pragma unroll
            for (int kc = 0; kc < 4; ++kc) {
                h8 bf = *(const h8*)&s_k[(nt * 16 + ln) * 128 + kc * 32 + quad * 8];
                sc[nt] = mfma16(qf[kc], bf, sc[nt]);
            }

        // mask + online softmax (per row r: global row = i0+16w+4*quad+r)
        float pmat[4][4], alpha[4];
        #pragma unroll
        for (int r = 0; r < 4; ++r) {
            int ig = i0 + w * 16 + quad * 4 + r;
            float vm = -INFINITY;
            #pragma unroll
            for (int nt = 0; nt < 4; ++nt) {
                int jg = j0 + nt * 16 + ln;
                float s = sc[nt][r];
                if (jg <= ig) s = -1e9f;           // faithful inverted mask
                sc[nt][r] = s;
                vm = fmaxf(vm, s);
            }
            #pragma unroll
            for (int off = 8; off; off >>= 1) vm = fmaxf(vm, __shfl_xor(vm, off, 64));
            float nm = fmaxf(mrow[r], vm);
            alpha[r] = __expf(mrow[r] - nm);       // first tile: exp(-inf)=0
            float rs = 0.f;
            #pragma unroll
            for (int nt = 0; nt < 4; ++nt) {
                float p = __expf(sc[nt][r] - nm);
                pmat[nt][r] = p; rs += p;
            }
            #pragma unroll
            for (int off = 8; off; off >>= 1) rs += __shfl_xor(rs, off, 64);
            lrow[r] = lrow[r] * alpha[r] + rs;
            mrow[r] = nm;
        }
        #pragma unroll
        for (int dt = 0; dt < 8; ++dt)
            #pragma unroll
            for (int r = 0; r < 4; ++r) O[dt][r] *= alpha[r];

        // P: C-layout -> LDS -> A-layout (m120 round trip)
        #pragma unroll
        for (int nt = 0; nt < 4; ++nt)
            #pragma unroll
            for (int r = 0; r < 4; ++r)
                s_p[w][(quad * 4 + r) * 64 + nt * 16 + ln] = (_Float16)pmat[nt][r];

        // O += P V  (B-frag from transposed V: contiguous ds_read_b128)
        #pragma unroll
        for (int jc = 0; jc < 2; ++jc) {
            h8 ap = *(const h8*)&s_p[w][ln * 64 + jc * 32 + quad * 8];
            #pragma unroll
            for (int dt = 0; dt < 8; ++dt) {
                h8 bv = *(const h8*)&s_vt[(dt * 16 + ln) * 64 + jc * 32 + quad * 8];
                O[dt] = mfma16(ap, bv, O[dt]);
            }
        }
        __syncthreads();
    }

    // epilogue: O / l  (row N-1 is garbage here; fixup kernel overwrites it)
    float inv_l[4];
    #pragma unroll
    for (int r = 0; r < 4; ++r) inv_l[r] = 1.0f / lrow[r];
    #pragma unroll
    for (int dt = 0; dt < 8; ++dt)
        #pragma unroll
        for (int r = 0; r < 4; ++r)
            ah[((size_t)(b * NN + i0 + w * 16 + quad * 4 + r)) * HDIM + h * DD +
               dt * 16 + ln] = (_Float16)(O[dt][r] * inv_l[r]);
}

// Row N-1: all scores masked -> softmax uniform over ALL N keys -> mean(V).
__global__ void fixup_lastrow_k(const _Float16* __restrict__ kvp,
                                _Float16* __restrict__ ah) {
    int b = blockIdx.x >> 2, kvh = blockIdx.x & 3, d = threadIdx.x;  // 128 thr
    float s = 0.f;
    for (int j = 0; j < NN; ++j)
        s += (float)kvp[((size_t)(b * NN + j)) * KVW + 512 + kvh * DD + d];
    float mean = s * (1.0f / NN);
    #pragma unroll
    for (int r = 0; r < 4; ++r) {
        int h = r * 4 + kvh;    // heads with h % 4 == kvh
        ah[((size_t)(b * NN + NN - 1)) * HDIM + h * DD + d] = (_Float16)mean;
    }
}

extern "C" void kernel_launch(void* const* d_in, const int* in_sizes, int n_in,
                              void* d_out, int out_size, void* d_ws, size_t ws_size,
                              hipStream_t stream) {
    const float* tokens = (const float*)d_in[0];
    const float* norm_w = (const float*)d_in[1];
    const float* Wq = (const float*)d_in[2];
    const float* bq = (const float*)d_in[3];
    const float* Wk = (const float*)d_in[4];
    const float* bk = (const float*)d_in[5];
    const float* Wv = (const float*)d_in[6];
    const float* bv = (const float*)d_in[7];
    const float* Wo = (const float*)d_in[8];
    const float* bo = (const float*)d_in[9];
    float* out = (float*)d_out;

    char* ws = (char*)d_ws;
    _Float16* x_h   = (_Float16*)(ws);                        // 16 MB
    _Float16* wq_h  = (_Float16*)(ws + 16777216);             // 8 MB
    _Float16* wkv_h = (_Float16*)(ws + 25165824);             // 4 MB
    _Float16* wo_h  = (_Float16*)(ws + 29360128);             // 8 MB
    float*    bkv   = (float*)   (ws + 37748736);             // 4 KB
    _Float16* q_h   = (_Float16*)(ws + 37752832);             // 16 MB
    _Float16* kv_h  = (_Float16*)(ws + 54530048);             // 8 MB
    _Float16* a_h   = (_Float16*)(ws + 62918656);             // 16 MB  (total ~76 MB)

    rmsnorm_k<<<MTOK, 256, 0, stream>>>(tokens, norm_w, x_h);
    cvt_k<<<4096, 256, 0, stream>>>(Wq, wq_h, HDIM * HDIM);
    cvt_k<<<1024, 256, 0, stream>>>(Wk, wkv_h, 512 * HDIM);
    cvt_k<<<1024, 256, 0, stream>>>(Wv, wkv_h + 512 * HDIM, 512 * HDIM);
    cvt_k<<<4096, 256, 0, stream>>>(Wo, wo_h, HDIM * HDIM);
    biascat_k<<<4, 256, 0, stream>>>(bk, bv, bkv);

    gemm_bt<0><<<dim3(HDIM / 128, MTOK / 128), 256, 0, stream>>>(
        x_h, wq_h, bq, (void*)q_h, HDIM, HDIM);
    gemm_bt<0><<<dim3(KVW / 128, MTOK / 128), 256, 0, stream>>>(
        x_h, wkv_h, bkv, (void*)kv_h, KVW, HDIM);

    attn_k<<<dim3(NN / 64, NHD, BB), 256, 0, stream>>>(q_h, kv_h, a_h);
    fixup_lastrow_k<<<BB * KVHD, 128, 0, stream>>>(kv_h, a_h);

    gemm_bt<1><<<dim3(HDIM / 128, MTOK / 128), 256, 0, stream>>>(
        a_h, wo_h, bo, (void*)out, HDIM, HDIM);
}